// Round 8
// baseline (127.971 us; speedup 1.0000x reference)
//
#include <hip/hip_runtime.h>
#include <math.h>

#define NJ  64        // j-axis chunks per direction
#define CB  256       // chamfer block size (threads)
#define IPT 4         // x-points per thread
#define CHUNK_MAX (((10000 + NJ - 1) / NJ) + 8)

// ---------------------------------------------------------------------------
// device helper: rigid transform (v+t) then Rx, Ry, Rz — EXACT op order of ref
// ---------------------------------------------------------------------------
__device__ __forceinline__ void xform(float x, float y, float z,
                                      float tx, float ty, float tz,
                                      float cx, float sx, float cy, float sy,
                                      float cz, float sz,
                                      float& ox, float& oy, float& oz)
{
    x += tx; y += ty; z += tz;
    float x1 = x;
    float y1 = cx*y - sx*z;
    float z1 = sx*y + cx*z;
    float x2 =  cy*x1 + sy*z1;
    float y2 = y1;
    float z2 = -sy*x1 + cy*z1;
    ox = cz*x2 - sz*y2;
    oy = sz*x2 + cz*y2;
    oz = z2;
}

// ---------------------------------------------------------------------------
// K1: fused transform (blocks [0,nbT)) + sample mov + sample fix.
// Block 0 / thread 0 also zeroes out[0] (loss accumulator for k_combine's
// stream-ordered atomicAdd; harness poisons d_out before every replay).
// ---------------------------------------------------------------------------
__global__ void k_prep(const float* __restrict__ vertsM, const int* __restrict__ facesM,
                       const int* __restrict__ fidxM, const float* __restrict__ uvM,
                       float4* __restrict__ ptsM, float4* __restrict__ nrmM,
                       const float* __restrict__ vertsF, const int* __restrict__ facesF,
                       const int* __restrict__ fidxF, const float* __restrict__ uvF,
                       float4* __restrict__ ptsF, float4* __restrict__ nrmF,
                       const float* __restrict__ trans,
                       const float* __restrict__ ax,
                       const float* __restrict__ ay,
                       const float* __restrict__ az,
                       float* __restrict__ lossOut,
                       float* __restrict__ pOut,
                       int V, int N, int nbT, int nbS)
{
    const float D2R = 0.017453292519943295f;
    int b = blockIdx.x;

    if (b == 0 && threadIdx.x == 0) lossOut[0] = 0.0f;

    if (b < nbT) {
        int i = b * blockDim.x + threadIdx.x;
        if (i >= V) return;
        float txr = ax[0]*D2R, tyr = ay[0]*D2R, tzr = az[0]*D2R;
        float cx = cosf(txr), sx = sinf(txr);
        float cy = cosf(tyr), sy = sinf(tyr);
        float cz = cosf(tzr), sz = sinf(tzr);
        float ox, oy, oz;
        xform(vertsM[3*i+0], vertsM[3*i+1], vertsM[3*i+2],
              trans[0], trans[1], trans[2], cx, sx, cy, sy, cz, sz, ox, oy, oz);
        pOut[3*i+0] = ox; pOut[3*i+1] = oy; pOut[3*i+2] = oz;
        return;
    }

    int bb = b - nbT;
    int which = (bb >= nbS) ? 1 : 0;            // 0 = moving, 1 = fixed
    int bx = which ? bb - nbS : bb;
    int i = bx * blockDim.x + threadIdx.x;
    if (i >= N) return;

    const float* verts = which ? vertsF : vertsM;
    const int*   faces = which ? facesF : facesM;
    const int*   fidx  = which ? fidxF  : fidxM;
    const float* uv    = which ? uvF    : uvM;
    float4* ptsS = which ? ptsF : ptsM;
    float4* nrm  = which ? nrmF : nrmM;

    int f  = fidx[i];
    int i0 = faces[3*f+0], i1 = faces[3*f+1], i2 = faces[3*f+2];
    float v0x = verts[3*i0+0], v0y = verts[3*i0+1], v0z = verts[3*i0+2];
    float v1x = verts[3*i1+0], v1y = verts[3*i1+1], v1z = verts[3*i1+2];
    float v2x = verts[3*i2+0], v2y = verts[3*i2+1], v2z = verts[3*i2+2];

    if (!which) {
        float txr = ax[0]*D2R, tyr = ay[0]*D2R, tzr = az[0]*D2R;
        float cx = cosf(txr), sx = sinf(txr);
        float cy = cosf(tyr), sy = sinf(tyr);
        float cz = cosf(tzr), sz = sinf(tzr);
        xform(v0x,v0y,v0z, trans[0],trans[1],trans[2], cx,sx,cy,sy,cz,sz, v0x,v0y,v0z);
        xform(v1x,v1y,v1z, trans[0],trans[1],trans[2], cx,sx,cy,sy,cz,sz, v1x,v1y,v1z);
        xform(v2x,v2y,v2z, trans[0],trans[1],trans[2], cx,sx,cy,sy,cz,sz, v2x,v2y,v2z);
    }

    float su = sqrtf(uv[2*i+0]);
    float vv = uv[2*i+1];
    float a = 1.0f - su;
    float bq = su * (1.0f - vv);
    float c = su * vv;
    float px = a*v0x + bq*v1x + c*v2x;
    float py = a*v0y + bq*v1y + c*v2y;
    float pz = a*v0z + bq*v1z + c*v2z;

    float e1x = v1x - v0x, e1y = v1y - v0y, e1z = v1z - v0z;
    float e2x = v2x - v0x, e2y = v2y - v0y, e2z = v2z - v0z;
    float nx = e1y*e2z - e1z*e2y;
    float ny = e1z*e2x - e1x*e2z;
    float nz = e1x*e2y - e1y*e2x;
    float nn = sqrtf(nx*nx + ny*ny + nz*nz) + 1e-8f;
    nx /= nn; ny /= nn; nz /= nn;

    ptsS[i] = make_float4(px, py, pz, px*px + py*py + pz*pz);
    nrm[i]  = make_float4(nx, ny, nz, 0.0f);
}

// ---------------------------------------------------------------------------
// K2: both chamfer directions, per-chunk MIN VALUE only (no index tracking).
// d' = |y|^2 - 2 x.y (3-FMA chain).  j processed in pairs with min3 fusion:
// best = fminf(fminf(d0,d1), best).  Index recovered later by rescan.
// Tile padded with +INF sentinels so the pair loop needs no tail.
// ---------------------------------------------------------------------------
__global__ void k_cham2(const float4* __restrict__ Pm, const float4* __restrict__ Pf,
                        float* __restrict__ pv, int N)
{
    int dir = blockIdx.z;
    const float4* X = dir ? Pf : Pm;
    const float4* Y = dir ? Pm : Pf;
    float* out = pv + (size_t)dir * NJ * N;

    __shared__ float4 tile[CHUNK_MAX];
    int chunk = blockIdx.y;
    int j0 = (int)(((long long)N * chunk) / NJ);
    int j1 = (int)(((long long)N * (chunk + 1)) / NJ);
    int cnt = j1 - j0;
    for (int t = threadIdx.x; t < cnt; t += CB) tile[t] = Y[j0 + t];
    if (threadIdx.x < 2) tile[cnt + threadIdx.x] = make_float4(0.f, 0.f, 0.f, 3.4e38f);
    __syncthreads();

    int ibase = blockIdx.x * CB * IPT + threadIdx.x;

    float xs0[IPT], xs1[IPT], xs2[IPT];
    #pragma unroll
    for (int p = 0; p < IPT; ++p) {
        int i = ibase + p * CB;
        float4 x = (i < N) ? X[i] : make_float4(0.f, 0.f, 0.f, 0.f);
        xs0[p] = -2.0f * x.x;
        xs1[p] = -2.0f * x.y;
        xs2[p] = -2.0f * x.z;
    }
    float best[IPT];
    #pragma unroll
    for (int p = 0; p < IPT; ++p) best[p] = 3.4e38f;

    int cnt2 = (cnt + 1) & ~1;                   // even (sentinel covers tail)
    #pragma unroll 2
    for (int jj = 0; jj < cnt2; jj += 2) {
        float4 y0 = tile[jj];
        float4 y1 = tile[jj + 1];
        #pragma unroll
        for (int p = 0; p < IPT; ++p) {
            float d0 = fmaf(xs0[p], y0.x, fmaf(xs1[p], y0.y, fmaf(xs2[p], y0.z, y0.w)));
            float d1 = fmaf(xs0[p], y1.x, fmaf(xs1[p], y1.y, fmaf(xs2[p], y1.z, y1.w)));
            best[p] = fminf(fminf(d0, d1), best[p]);   // -> v_min3_f32
        }
    }
    #pragma unroll
    for (int p = 0; p < IPT; ++p) {
        int i = ibase + p * CB;
        if (i < N) out[(size_t)chunk*N + i] = best[p];
    }
}

// ---------------------------------------------------------------------------
// K3: per point: find first chunk attaining the global min (strict <,
// ascending = numpy first-occurrence), rescan that chunk with the bitwise-
// identical fmaf chain to recover the argmin index, add |x|^2 back, add
// normal-cosine term, block-reduce, atomicAdd to loss.
// ---------------------------------------------------------------------------
__global__ void k_combine(const float* __restrict__ pv,
                          const float4* __restrict__ Pm, const float4* __restrict__ Pf,
                          const float4* __restrict__ n_m, const float4* __restrict__ n_f,
                          float* __restrict__ lossOut, float invN, int N)
{
    int dir = blockIdx.y;
    const float*  pvd = pv + (size_t)dir * NJ * N;
    const float4* Xp  = dir ? Pf : Pm;
    const float4* Yp  = dir ? Pm : Pf;

    int i = blockIdx.x * 256 + threadIdx.x;
    float term = 0.0f;
    if (i < N) {
        float best = 3.4e38f; int bc = 0;
        #pragma unroll
        for (int c = 0; c < NJ; ++c) {
            float v = pvd[(size_t)c*N + i];
            if (v < best) { best = v; bc = c; }
        }
        float4 x = Xp[i];
        float xs0 = -2.0f*x.x, xs1 = -2.0f*x.y, xs2 = -2.0f*x.z;
        int j0 = (int)(((long long)N * bc) / NJ);
        int j1 = (int)(((long long)N * (bc + 1)) / NJ);
        float bd = 3.4e38f; int bj = j0;
        for (int j = j0; j < j1; ++j) {
            float4 y = Yp[j];
            float d = fmaf(xs0, y.x, fmaf(xs1, y.y, fmaf(xs2, y.z, y.w)));
            if (d < bd) { bd = d; bj = j; }
        }
        float4 a = dir ? n_f[i]  : n_m[i];
        float4 b = dir ? n_m[bj] : n_f[bj];
        term = (best + x.w) + 1.0f - fabsf(a.x*b.x + a.y*b.y + a.z*b.z);
    }
    __shared__ float red[256];
    red[threadIdx.x] = term;
    __syncthreads();
    for (int s = 128; s > 0; s >>= 1) {
        if (threadIdx.x < s) red[threadIdx.x] += red[threadIdx.x + s];
        __syncthreads();
    }
    if (threadIdx.x == 0) atomicAdd(lossOut, red[0] * invN);
}

// ---------------------------------------------------------------------------
extern "C" void kernel_launch(void* const* d_in, const int* in_sizes, int n_in,
                              void* d_out, int out_size, void* d_ws, size_t ws_size,
                              hipStream_t stream)
{
    const float* verts_mov = (const float*)d_in[0];
    const int*   faces_mov = (const int*)  d_in[1];
    const float* verts_fix = (const float*)d_in[2];
    const int*   faces_fix = (const int*)  d_in[3];
    const float* trans     = (const float*)d_in[4];
    const float* ax        = (const float*)d_in[5];
    const float* ay        = (const float*)d_in[6];
    const float* az        = (const float*)d_in[7];
    const int*   fidx_mov  = (const int*)  d_in[8];
    const float* uv_mov    = (const float*)d_in[9];
    const int*   fidx_fix  = (const int*)  d_in[10];
    const float* uv_fix    = (const float*)d_in[11];

    int V = in_sizes[0] / 3;
    int N = in_sizes[8];

    float* out = (float*)d_out;
    float* p   = out + 1;           // transformed verts region of output

    // workspace layout (floats)
    float*  ws      = (float*)d_ws;
    float4* ptsS_m  = (float4*)(ws + 0*4*N);
    float4* n_m     = (float4*)(ws + 1*4*N);
    float4* ptsS_f  = (float4*)(ws + 2*4*N);
    float4* n_f     = (float4*)(ws + 3*4*N);
    float*  pv      = ws + 16*N;                      // 2 * NJ * N floats

    int nbT = (V + 255) / 256;
    int nbS = (N + 255) / 256;
    k_prep<<<nbT + 2*nbS, 256, 0, stream>>>(verts_mov, faces_mov, fidx_mov, uv_mov,
                                            ptsS_m, n_m,
                                            verts_fix, faces_fix, fidx_fix, uv_fix,
                                            ptsS_f, n_f,
                                            trans, ax, ay, az, out, p, V, N, nbT, nbS);

    dim3 gc((N + CB*IPT - 1)/(CB*IPT), NJ, 2);
    k_cham2<<<gc, CB, 0, stream>>>(ptsS_m, ptsS_f, pv, N);

    int GX = (N + 255)/256;
    dim3 gk(GX, 2);
    k_combine<<<gk, 256, 0, stream>>>(pv, ptsS_m, ptsS_f, n_m, n_f, out, 1.0f/(float)N, N);
}

// Round 10
// 121.867 us; speedup vs baseline: 1.0501x; 1.0501x over previous
//
#include <hip/hip_runtime.h>
#include <math.h>

#define NJ  64        // j-axis chunks per direction (== wavefront size)
#define CB  256       // chamfer block size (threads)
#define IPT 4         // x-points per thread
#define CHUNK_MAX (((10000 + NJ - 1) / NJ) + 8)

static_assert(NJ == 64, "k_combine maps chunks onto the 64 lanes of a wave");

// ---------------------------------------------------------------------------
// device helper: rigid transform (v+t) then Rx, Ry, Rz — EXACT op order of ref
// ---------------------------------------------------------------------------
__device__ __forceinline__ void xform(float x, float y, float z,
                                      float tx, float ty, float tz,
                                      float cx, float sx, float cy, float sy,
                                      float cz, float sz,
                                      float& ox, float& oy, float& oz)
{
    x += tx; y += ty; z += tz;
    float x1 = x;
    float y1 = cx*y - sx*z;
    float z1 = sx*y + cx*z;
    float x2 =  cy*x1 + sy*z1;
    float y2 = y1;
    float z2 = -sy*x1 + cy*z1;
    ox = cz*x2 - sz*y2;
    oy = sz*x2 + cz*y2;
    oz = z2;
}

// ---------------------------------------------------------------------------
// K1: fused transform (blocks [0,nbT)) + sample mov + sample fix.
// Block 0 / thread 0 also zeroes out[0] (loss accumulator for k_combine's
// stream-ordered atomicAdd; harness poisons d_out before every replay).
// ---------------------------------------------------------------------------
__global__ void k_prep(const float* __restrict__ vertsM, const int* __restrict__ facesM,
                       const int* __restrict__ fidxM, const float* __restrict__ uvM,
                       float4* __restrict__ ptsM, float4* __restrict__ nrmM,
                       const float* __restrict__ vertsF, const int* __restrict__ facesF,
                       const int* __restrict__ fidxF, const float* __restrict__ uvF,
                       float4* __restrict__ ptsF, float4* __restrict__ nrmF,
                       const float* __restrict__ trans,
                       const float* __restrict__ ax,
                       const float* __restrict__ ay,
                       const float* __restrict__ az,
                       float* __restrict__ lossOut,
                       float* __restrict__ pOut,
                       int V, int N, int nbT, int nbS)
{
    const float D2R = 0.017453292519943295f;
    int b = blockIdx.x;

    if (b == 0 && threadIdx.x == 0) lossOut[0] = 0.0f;

    if (b < nbT) {
        int i = b * blockDim.x + threadIdx.x;
        if (i >= V) return;
        float txr = ax[0]*D2R, tyr = ay[0]*D2R, tzr = az[0]*D2R;
        float cx = cosf(txr), sx = sinf(txr);
        float cy = cosf(tyr), sy = sinf(tyr);
        float cz = cosf(tzr), sz = sinf(tzr);
        float ox, oy, oz;
        xform(vertsM[3*i+0], vertsM[3*i+1], vertsM[3*i+2],
              trans[0], trans[1], trans[2], cx, sx, cy, sy, cz, sz, ox, oy, oz);
        pOut[3*i+0] = ox; pOut[3*i+1] = oy; pOut[3*i+2] = oz;
        return;
    }

    int bb = b - nbT;
    int which = (bb >= nbS) ? 1 : 0;            // 0 = moving, 1 = fixed
    int bx = which ? bb - nbS : bb;
    int i = bx * blockDim.x + threadIdx.x;
    if (i >= N) return;

    const float* verts = which ? vertsF : vertsM;
    const int*   faces = which ? facesF : facesM;
    const int*   fidx  = which ? fidxF  : fidxM;
    const float* uv    = which ? uvF    : uvM;
    float4* ptsS = which ? ptsF : ptsM;
    float4* nrm  = which ? nrmF : nrmM;

    int f  = fidx[i];
    int i0 = faces[3*f+0], i1 = faces[3*f+1], i2 = faces[3*f+2];
    float v0x = verts[3*i0+0], v0y = verts[3*i0+1], v0z = verts[3*i0+2];
    float v1x = verts[3*i1+0], v1y = verts[3*i1+1], v1z = verts[3*i1+2];
    float v2x = verts[3*i2+0], v2y = verts[3*i2+1], v2z = verts[3*i2+2];

    if (!which) {
        float txr = ax[0]*D2R, tyr = ay[0]*D2R, tzr = az[0]*D2R;
        float cx = cosf(txr), sx = sinf(txr);
        float cy = cosf(tyr), sy = sinf(tyr);
        float cz = cosf(tzr), sz = sinf(tzr);
        xform(v0x,v0y,v0z, trans[0],trans[1],trans[2], cx,sx,cy,sy,cz,sz, v0x,v0y,v0z);
        xform(v1x,v1y,v1z, trans[0],trans[1],trans[2], cx,sx,cy,sy,cz,sz, v1x,v1y,v1z);
        xform(v2x,v2y,v2z, trans[0],trans[1],trans[2], cx,sx,cy,sy,cz,sz, v2x,v2y,v2z);
    }

    float su = sqrtf(uv[2*i+0]);
    float vv = uv[2*i+1];
    float a = 1.0f - su;
    float bq = su * (1.0f - vv);
    float c = su * vv;
    float px = a*v0x + bq*v1x + c*v2x;
    float py = a*v0y + bq*v1y + c*v2y;
    float pz = a*v0z + bq*v1z + c*v2z;

    float e1x = v1x - v0x, e1y = v1y - v0y, e1z = v1z - v0z;
    float e2x = v2x - v0x, e2y = v2y - v0y, e2z = v2z - v0z;
    float nx = e1y*e2z - e1z*e2y;
    float ny = e1z*e2x - e1x*e2z;
    float nz = e1x*e2y - e1y*e2x;
    float nn = sqrtf(nx*nx + ny*ny + nz*nz) + 1e-8f;
    nx /= nn; ny /= nn; nz /= nn;

    ptsS[i] = make_float4(px, py, pz, px*px + py*py + pz*pz);
    nrm[i]  = make_float4(nx, ny, nz, 0.0f);
}

// ---------------------------------------------------------------------------
// K2: both chamfer directions, per-chunk MIN VALUE only (no index tracking).
// d' = |y|^2 - 2 x.y (3-FMA chain).  j processed in pairs with min3 fusion:
// best = fminf(fminf(d0,d1), best).  Index recovered later by rescan.
// Tile padded with +INF sentinels so the pair loop needs no tail.
// ---------------------------------------------------------------------------
__global__ void k_cham2(const float4* __restrict__ Pm, const float4* __restrict__ Pf,
                        float* __restrict__ pv, int N)
{
    int dir = blockIdx.z;
    const float4* X = dir ? Pf : Pm;
    const float4* Y = dir ? Pm : Pf;
    float* out = pv + (size_t)dir * NJ * N;

    __shared__ float4 tile[CHUNK_MAX];
    int chunk = blockIdx.y;
    int j0 = (int)(((long long)N * chunk) / NJ);
    int j1 = (int)(((long long)N * (chunk + 1)) / NJ);
    int cnt = j1 - j0;
    for (int t = threadIdx.x; t < cnt; t += CB) tile[t] = Y[j0 + t];
    if (threadIdx.x < 2) tile[cnt + threadIdx.x] = make_float4(0.f, 0.f, 0.f, 3.4e38f);
    __syncthreads();

    int ibase = blockIdx.x * CB * IPT + threadIdx.x;

    float xs0[IPT], xs1[IPT], xs2[IPT];
    #pragma unroll
    for (int p = 0; p < IPT; ++p) {
        int i = ibase + p * CB;
        float4 x = (i < N) ? X[i] : make_float4(0.f, 0.f, 0.f, 0.f);
        xs0[p] = -2.0f * x.x;
        xs1[p] = -2.0f * x.y;
        xs2[p] = -2.0f * x.z;
    }
    float best[IPT];
    #pragma unroll
    for (int p = 0; p < IPT; ++p) best[p] = 3.4e38f;

    int cnt2 = (cnt + 1) & ~1;                   // even (sentinel covers tail)
    #pragma unroll 2
    for (int jj = 0; jj < cnt2; jj += 2) {
        float4 y0 = tile[jj];
        float4 y1 = tile[jj + 1];
        #pragma unroll
        for (int p = 0; p < IPT; ++p) {
            float d0 = fmaf(xs0[p], y0.x, fmaf(xs1[p], y0.y, fmaf(xs2[p], y0.z, y0.w)));
            float d1 = fmaf(xs0[p], y1.x, fmaf(xs1[p], y1.y, fmaf(xs2[p], y1.z, y1.w)));
            best[p] = fminf(fminf(d0, d1), best[p]);   // -> v_min3_f32
        }
    }
    #pragma unroll
    for (int p = 0; p < IPT; ++p) {
        int i = ibase + p * CB;
        if (i < N) out[(size_t)chunk*N + i] = best[p];
    }
}

// ---------------------------------------------------------------------------
// K3: WAVE-COOPERATIVE combine.  One wave per (point, dir).
// Stage 1: lane l holds chunk l's min; shuffle argmin, first-chunk tie-break.
// Stage 2: 64 lanes cooperatively rescan the winning chunk (coalesced j0+lane
// stride-64 loads), bitwise-identical fmaf chain; reduce prefers smaller j on
// ties -> exact numpy first-occurrence argmin.  16 waves/block, LDS reduce,
// one atomicAdd per block.
// ---------------------------------------------------------------------------
__global__ __launch_bounds__(1024)
void k_combine(const float* __restrict__ pv,
               const float4* __restrict__ Pm, const float4* __restrict__ Pf,
               const float4* __restrict__ n_m, const float4* __restrict__ n_f,
               float* __restrict__ lossOut, float invN, int N)
{
    int dir = blockIdx.y;
    const float*  pvd = pv + (size_t)dir * NJ * N;
    const float4* Xp  = dir ? Pf : Pm;
    const float4* Yp  = dir ? Pm : Pf;

    int wid  = threadIdx.x >> 6;          // wave id in block (0..15)
    int lane = threadIdx.x & 63;
    int i    = blockIdx.x * 16 + wid;     // one point per wave

    float term = 0.0f;
    if (i < N) {
        // ---- stage 1: chunk argmin across the wave ----
        float v  = pvd[(size_t)lane * N + i];
        int   bc = lane;
        #pragma unroll
        for (int off = 32; off > 0; off >>= 1) {
            float ov = __shfl_down(v, off, 64);
            int   oc = __shfl_down(bc, off, 64);
            if (ov < v || (ov == v && oc < bc)) { v = ov; bc = oc; }
        }
        v  = __shfl(v, 0, 64);
        bc = __shfl(bc, 0, 64);

        // ---- stage 2: cooperative rescan of chunk bc ----
        float4 x = Xp[i];
        float xs0 = -2.0f*x.x, xs1 = -2.0f*x.y, xs2 = -2.0f*x.z;
        int j0 = (int)(((long long)N * bc) / NJ);
        int j1 = (int)(((long long)N * (bc + 1)) / NJ);
        float bd = 3.4e38f; int bj = 0x7fffffff;
        for (int j = j0 + lane; j < j1; j += 64) {
            float4 y = Yp[j];
            float d = fmaf(xs0, y.x, fmaf(xs1, y.y, fmaf(xs2, y.z, y.w)));
            if (d < bd) { bd = d; bj = j; }      // per-lane first occurrence
        }
        #pragma unroll
        for (int off = 32; off > 0; off >>= 1) {
            float od = __shfl_down(bd, off, 64);
            int   oj = __shfl_down(bj, off, 64);
            if (od < bd || (od == bd && oj < bj)) { bd = od; bj = oj; }
        }
        if (lane == 0) {
            float4 a = dir ? n_f[i]  : n_m[i];
            float4 b = dir ? n_m[bj] : n_f[bj];
            term = (v + x.w) + 1.0f - fabsf(a.x*b.x + a.y*b.y + a.z*b.z);
        }
    }

    __shared__ float red[16];
    if (lane == 0) red[wid] = term;
    __syncthreads();
    if (threadIdx.x == 0) {
        float s = 0.0f;
        #pragma unroll
        for (int w = 0; w < 16; ++w) s += red[w];
        atomicAdd(lossOut, s * invN);
    }
}

// ---------------------------------------------------------------------------
extern "C" void kernel_launch(void* const* d_in, const int* in_sizes, int n_in,
                              void* d_out, int out_size, void* d_ws, size_t ws_size,
                              hipStream_t stream)
{
    const float* verts_mov = (const float*)d_in[0];
    const int*   faces_mov = (const int*)  d_in[1];
    const float* verts_fix = (const float*)d_in[2];
    const int*   faces_fix = (const int*)  d_in[3];
    const float* trans     = (const float*)d_in[4];
    const float* ax        = (const float*)d_in[5];
    const float* ay        = (const float*)d_in[6];
    const float* az        = (const float*)d_in[7];
    const int*   fidx_mov  = (const int*)  d_in[8];
    const float* uv_mov    = (const float*)d_in[9];
    const int*   fidx_fix  = (const int*)  d_in[10];
    const float* uv_fix    = (const float*)d_in[11];

    int V = in_sizes[0] / 3;
    int N = in_sizes[8];

    float* out = (float*)d_out;
    float* p   = out + 1;           // transformed verts region of output

    // workspace layout (floats)
    float*  ws      = (float*)d_ws;
    float4* ptsS_m  = (float4*)(ws + 0*4*N);
    float4* n_m     = (float4*)(ws + 1*4*N);
    float4* ptsS_f  = (float4*)(ws + 2*4*N);
    float4* n_f     = (float4*)(ws + 3*4*N);
    float*  pv      = ws + 16*N;                      // 2 * NJ * N floats

    int nbT = (V + 255) / 256;
    int nbS = (N + 255) / 256;
    k_prep<<<nbT + 2*nbS, 256, 0, stream>>>(verts_mov, faces_mov, fidx_mov, uv_mov,
                                            ptsS_m, n_m,
                                            verts_fix, faces_fix, fidx_fix, uv_fix,
                                            ptsS_f, n_f,
                                            trans, ax, ay, az, out, p, V, N, nbT, nbS);

    dim3 gc((N + CB*IPT - 1)/(CB*IPT), NJ, 2);
    k_cham2<<<gc, CB, 0, stream>>>(ptsS_m, ptsS_f, pv, N);

    dim3 gk((N + 15)/16, 2);
    k_combine<<<gk, 1024, 0, stream>>>(pv, ptsS_m, ptsS_f, n_m, n_f, out, 1.0f/(float)N, N);
}